// Round 7
// baseline (183.021 us; speedup 1.0000x reference)
//
#include <hip/hip_runtime.h>
#include <hip/hip_bf16.h>

typedef unsigned short u16;
typedef unsigned int u32;
typedef float f32x4 __attribute__((ext_vector_type(4)));
typedef short bf16x8 __attribute__((ext_vector_type(8)));

// ---- constants (B=2, S=2048, E=1024, H=16, D=64) ----
#define BB 2
#define SS 2048
#define EE 1024
#define HH 16
#define DD 64
// q pre-scale: 1/sqrt(D) * log2(e) — scores land directly in exp2 domain.
#define QSCALE 0.18033688011f

__device__ __forceinline__ u16 f2bf(float f) {
    union { u32 i; float f; } x; x.f = f;
    return (u16)((x.i + 0x7FFFu + ((x.i >> 16) & 1u)) >> 16);
}
__device__ __forceinline__ u32 pkbf(float a, float b) {
    __hip_bfloat162 h = __float22bfloat162_rn(make_float2(a, b));
    union { __hip_bfloat162 h; u32 u; } c; c.h = h; return c.u;
}

#define MFMA16(a, b, c) __builtin_amdgcn_mfma_f32_16x16x32_bf16((a), (b), (c), 0, 0, 0)

// async global->LDS DMA, 16B per lane; LDS dest = wave-uniform base + lane*16
__device__ __forceinline__ void gld16(const u16* g, u16* l) {
    __builtin_amdgcn_global_load_lds(
        (const __attribute__((address_space(1))) void*)g,
        (__attribute__((address_space(3))) void*)l,
        16, 0, 0);
}

// ============================================================
// fused fp32 -> bf16 convert of x | W_attn | W_proj into contiguous ws
// ============================================================
__global__ __launch_bounds__(256) void convert_all(
    const float* __restrict__ x, const float* __restrict__ wa,
    const float* __restrict__ wp, u16* __restrict__ dst)
{
    const size_t n0 = (size_t)4096 * 1024;
    const size_t n1 = n0 + (size_t)3072 * 1024;
    size_t i = ((size_t)blockIdx.x * 256 + threadIdx.x) * 4;
    const float* s;
    size_t off;
    if (i < n0)      { s = x;  off = 0;  }
    else if (i < n1) { s = wa; off = n0; }
    else             { s = wp; off = n1; }
    float4 v = *(const float4*)(s + (i - off));
    uint2 o;
    o.x = pkbf(v.x, v.y);
    o.y = pkbf(v.z, v.w);
    *(uint2*)(dst + i) = o;
}

// ============================================================
// GEMM1 v4: qkv = x*W_attn^T + b_attn — 8-wave 128x128 tile,
// double-buffered gld16 staging. LDS 64 KB -> 2 blocks/CU. grid (24, 32).
// XCD note: id = x + 24y -> XCD = x%8 (24%8=0): each XCD owns 3 n-slices
// of W (0.79 MB, L2-resident across all y) — already the good orientation.
// ============================================================
__global__ __launch_bounds__(512, 4) void gemm_qkv(
    const u16* __restrict__ A, const u16* __restrict__ B, const float* __restrict__ bias,
    u16* __restrict__ Qo, u16* __restrict__ Ko, u16* __restrict__ Vto)
{
    __shared__ __align__(16) u16 SMEM[2][16384];   // [buf]{As[128*64] | Bs[128*64]}
    const int n0 = blockIdx.x * 128, m0 = blockIdx.y * 128;
    const int tid = threadIdx.x;
    const int wave = tid >> 6, lane = tid & 63;
    const int l16 = lane & 15, quad = lane >> 4;
    const int wm = wave >> 2, wn = wave & 3;       // 2x4 wave grid
    const int ldr = lane >> 3;
    const int csw = ((lane & 7) ^ ldr) * 8;        // swizzled k-chunk (elems)

    f32x4 acc[4][2];
#pragma unroll
    for (int i = 0; i < 4; ++i)
#pragma unroll
        for (int j = 0; j < 2; ++j) acc[i][j] = f32x4{0.f, 0.f, 0.f, 0.f};

    const int aorb = wave >> 2;                    // 0: stage A, 1: stage B
    const u16* stgsrc = aorb ? B : A;
    const int stgbase = aorb ? n0 : m0;
    const int stgoff = aorb ? 8192 : 0;

    auto stage = [&](int k0, int buf) {
        u16* stgbuf = &SMEM[buf][stgoff];
#pragma unroll
        for (int t = 0; t < 4; ++t) {
            const int c = (wave & 3) * 4 + t;      // 0..15
            const int row = c * 8 + ldr;
            gld16(stgsrc + (size_t)(stgbase + row) * 1024 + k0 + csw,
                  &stgbuf[c * 512 + lane * 8]);
        }
    };

    stage(0, 0);                                   // prologue
    for (int k0 = 0; k0 < 1024; k0 += 64) {
        const int cur = (k0 >> 6) & 1;
        // compiler emits vmcnt(0)+barrier: buf[cur] ready, buf^1 free
        __syncthreads();
        if (k0 + 64 < 1024) stage(k0 + 64, cur ^ 1);
        const u16* As = SMEM[cur];
        const u16* Bs = SMEM[cur] + 8192;
#pragma unroll
        for (int ks = 0; ks < 2; ++ks) {
            bf16x8 af[4], bf[2];
#pragma unroll
            for (int i = 0; i < 4; ++i)
                af[i] = *(const bf16x8*)&As[(wm * 64 + i * 16 + l16) * 64 +
                                            ((ks * 4 + quad) ^ (l16 & 7)) * 8];
#pragma unroll
            for (int j = 0; j < 2; ++j)
                bf[j] = *(const bf16x8*)&Bs[(wn * 32 + j * 16 + l16) * 64 +
                                            ((ks * 4 + quad) ^ (l16 & 7)) * 8];
#pragma unroll
            for (int i = 0; i < 4; ++i)
#pragma unroll
                for (int j = 0; j < 2; ++j)
                    acc[i][j] = MFMA16(af[i], bf[j], acc[i][j]);
        }
    }

    const int part = blockIdx.x >> 3;              // 0=q,1=k,2=v
    const int hbase = (blockIdx.x & 7) << 1;
    if (part != 2) {
        const int h = hbase + (wn >> 1);           // uniform per wave
#pragma unroll
        for (int j = 0; j < 2; ++j) {
            const int f = n0 + wn * 32 + j * 16 + l16;
            const int d = f & 63;
            const float bj = bias[f];
#pragma unroll
            for (int i = 0; i < 4; ++i) {
#pragma unroll
                for (int r = 0; r < 4; ++r) {
                    const int m = m0 + wm * 64 + i * 16 + quad * 4 + r;
                    const int b = m >> 11, s = m & 2047;
                    const float val = acc[i][j][r] + bj;
                    if (part == 0)
                        Qo[(((size_t)(b * HH + h)) * SS + s) * DD + d] = f2bf(val * QSCALE);
                    else
                        Ko[(((size_t)(b * HH + h)) * SS + s) * DD + d] = f2bf(val);
                }
            }
        }
    } else {
        // V: transpose C-tile (128 m x 128 f) through T (aliases SMEM[0]),
        // two m-half passes, coalesced 8B stores to [B,H,D,S].
        u16* T = SMEM[0];                          // 128 x 72 = 18432 B
#pragma unroll
        for (int wmr = 0; wmr < 2; ++wmr) {
            __syncthreads();
            if (wm == wmr) {
#pragma unroll
                for (int j = 0; j < 2; ++j) {
                    const float bj = bias[n0 + wn * 32 + j * 16 + l16];
#pragma unroll
                    for (int i = 0; i < 4; ++i) {
                        uint2 pw;
                        pw.x = pkbf(acc[i][j][0] + bj, acc[i][j][1] + bj);
                        pw.y = pkbf(acc[i][j][2] + bj, acc[i][j][3] + bj);
                        *(uint2*)&T[(wn * 32 + j * 16 + l16) * 72 + i * 16 + quad * 4] = pw;
                    }
                }
            }
            __syncthreads();
            const int frow = tid >> 2;             // 0..127 (f_local)
            const int qtr = tid & 3;
            const int h = hbase + (frow >> 6);
            const int d = frow & 63;
            const int mg = m0 + wmr * 64;
            const int b = mg >> 11, sbase = mg & 2047;
            u16* dstrow = Vto + (((size_t)(b * HH + h)) * DD + d) * SS + sbase;
#pragma unroll
            for (int l = 0; l < 4; ++l) {
                const int mo = qtr * 16 + l * 4;
                *(uint2*)(dstrow + mo) = *(const uint2*)&T[frow * 72 + mo];
            }
        }
    }
}

// ============================================================
// GEMM2 v5: out = o*W_proj^T + b_proj (fp32) — 64x128 tile, 8 waves,
// double-buffered staging, grid (64, 8) (XCD = m%8: A-rows L2-local,
// W_proj 2.1 MB L2-resident — R6 win, kept).
// ============================================================
__global__ __launch_bounds__(512, 4) void gemm_proj(
    const u16* __restrict__ A, const u16* __restrict__ B, const float* __restrict__ bias,
    float* __restrict__ out)
{
    __shared__ __align__(16) u16 SMEM[2][12288];   // [buf]{As[64*64] | Bs[128*64]}
    const int n0 = blockIdx.y * 128, m0 = blockIdx.x * 64;
    const int tid = threadIdx.x;
    const int wave = tid >> 6, lane = tid & 63;
    const int l16 = lane & 15, quad = lane >> 4;
    const int wm = wave >> 2, wn = wave & 3;       // 2x4 wave grid
    const int ldr = lane >> 3;
    const int csw = ((lane & 7) ^ ldr) * 8;

    f32x4 acc[2][2];
#pragma unroll
    for (int i = 0; i < 2; ++i)
#pragma unroll
        for (int j = 0; j < 2; ++j) acc[i][j] = f32x4{0.f, 0.f, 0.f, 0.f};

    auto stage = [&](int k0, int buf) {
#pragma unroll
        for (int t = 0; t < 3; ++t) {
            const int c = wave * 3 + t;            // 0..23: A chunks 0-7, B 8-23
            if (c < 8) {
                const int row = c * 8 + ldr;
                gld16(A + (size_t)(m0 + row) * 1024 + k0 + csw,
                      &SMEM[buf][c * 512 + lane * 8]);
            } else {
                const int c2 = c - 8;
                const int row = c2 * 8 + ldr;
                gld16(B + (size_t)(n0 + row) * 1024 + k0 + csw,
                      &SMEM[buf][4096 + c2 * 512 + lane * 8]);
            }
        }
    };

    stage(0, 0);                                   // prologue
    for (int k0 = 0; k0 < 1024; k0 += 64) {
        const int cur = (k0 >> 6) & 1;
        __syncthreads();
        if (k0 + 64 < 1024) stage(k0 + 64, cur ^ 1);
        const u16* As = SMEM[cur];
        const u16* Bs = SMEM[cur] + 4096;
#pragma unroll
        for (int ks = 0; ks < 2; ++ks) {
            bf16x8 af[2], bf[2];
#pragma unroll
            for (int i = 0; i < 2; ++i)
                af[i] = *(const bf16x8*)&As[(wm * 32 + i * 16 + l16) * 64 +
                                            ((ks * 4 + quad) ^ (l16 & 7)) * 8];
#pragma unroll
            for (int j = 0; j < 2; ++j)
                bf[j] = *(const bf16x8*)&Bs[(wn * 32 + j * 16 + l16) * 64 +
                                            ((ks * 4 + quad) ^ (l16 & 7)) * 8];
#pragma unroll
            for (int i = 0; i < 2; ++i)
#pragma unroll
                for (int j = 0; j < 2; ++j)
                    acc[i][j] = MFMA16(af[i], bf[j], acc[i][j]);
        }
    }
#pragma unroll
    for (int j = 0; j < 2; ++j) {
        const int f = n0 + wn * 32 + j * 16 + l16;
        const float bj = bias[f];
#pragma unroll
        for (int i = 0; i < 2; ++i) {
#pragma unroll
            for (int r = 0; r < 4; ++r) {
                const int m = m0 + wm * 32 + i * 16 + quad * 4 + r;
                out[(size_t)m * EE + f] = acc[i][j][r] + bj;
            }
        }
    }
}

// ============================================================
// MFMA flash attention v10: 32 q-rows per wave (QBLK=128 per block).
// DIAGNOSIS (R6): v8 was LDS-pipe-bound — all 4 waves read the full
// K/V tile (18 b128 reads ~240cy vs 16 MFMA ~78cy per wave-tile;
// 8 waves/CU -> ~1920cy LDS per tile ≈ observed phase time). Doubling
// q-rows/wave reuses every K/V fragment for TWO q-column blocks:
// per wave-tile 32 MFMA vs 20 b128 reads -> LDS per tile-CU 1152cy
// (-40%), staged K/V traffic halves (each K-tile serves 128 q-rows),
// while KEEPING 512 blocks = 2/CU (v9's 1/CU was the regression).
// Grid (32,16): x = bh (XCD locality), qi = 15-y (longest first).
// LDS: K 2x8K + V 2x8K + Ps 128x72x2 = 50 KB -> 2 blocks/CU.
// Depth-1 dbuf pipeline: barrier; stage(kb+1)->buf^1; compute buf[cur].
// ============================================================
__global__ __launch_bounds__(256, 2) void attn(
    const u16* __restrict__ Q, const u16* __restrict__ K, const u16* __restrict__ VT,
    u16* __restrict__ O)
{
    const int qi = 15 - (int)blockIdx.y;   // q-block of 128 rows, longest first
    const int bh = blockIdx.x;             // 0..31 -> XCD = bh % 8
    const int tid = threadIdx.x;
    const int wave = tid >> 6, lane = tid & 63;
    const int l16 = lane & 15, quad = lane >> 4;
    const int ldr = lane >> 3;
    const int csw = ((lane & 7) ^ ldr) * 8;
    __shared__ __align__(16) u16 Ks[2][64 * 64];
    __shared__ __align__(16) u16 Vts[2][64 * 64];
    __shared__ __align__(16) u16 Ps[128 * 72];

    const u16* qptr = Q + (size_t)bh * SS * DD;
    const u16* kptr = K + (size_t)bh * SS * DD;
    const u16* vtptr = VT + (size_t)bh * DD * SS;
    const int b = bh >> 4, h = bh & 15;

    // stage k-tile `t`: 4 waves x 2 chunks x (K row-block + V^T col-block)
    auto stage = [&](int t, int buf) {
#pragma unroll
        for (int c = 0; c < 2; ++c) {
            const int a0 = wave * 2 + c;
            const int row = a0 * 8 + ldr;
            gld16(kptr + (size_t)(t * 64 + row) * DD + csw,
                  &Ks[buf][a0 * 512 + lane * 8]);
            gld16(vtptr + (size_t)row * SS + t * 64 + csw,
                  &Vts[buf][a0 * 512 + lane * 8]);
        }
    };

    // Q in registers: wave owns rows qi*128 + wave*32 + qb*16 + l16
    bf16x8 bq[2][2];
#pragma unroll
    for (int qb = 0; qb < 2; ++qb) {
        const int qrow = qi * 128 + wave * 32 + qb * 16 + l16;
#pragma unroll
        for (int ks = 0; ks < 2; ++ks)
            bq[qb][ks] = *(const bf16x8*)(qptr + (size_t)qrow * DD + ks * 32 + quad * 8);
    }

    float lp[2] = {0.f, 0.f};
    f32x4 o_acc[4][2];
#pragma unroll
    for (int j = 0; j < 4; ++j)
#pragma unroll
        for (int qb = 0; qb < 2; ++qb) o_acc[j][qb] = f32x4{0.f, 0.f, 0.f, 0.f};

    const int kend = 2 * qi + 1;           // causal limit (64-row k-tiles)
    stage(0, 0);                           // prologue

    for (int kb = 0; kb <= kend; ++kb) {
        const int cur = kb & 1;
        // compiler-emitted vmcnt(0)+barrier: buf[cur] ready (staged last
        // phase), buf^1 has no readers left (read last phase).
        __syncthreads();
        if (kb < kend) stage(kb + 1, cur ^ 1);

        // S^T = K·Q^T : every ak fragment feeds BOTH q-column blocks
        f32x4 s[4][2];
#pragma unroll
        for (int j = 0; j < 4; ++j)
#pragma unroll
            for (int qb = 0; qb < 2; ++qb) s[j][qb] = f32x4{0.f, 0.f, 0.f, 0.f};
        __builtin_amdgcn_s_setprio(1);
#pragma unroll
        for (int ks = 0; ks < 2; ++ks) {
#pragma unroll
            for (int j = 0; j < 4; ++j) {
                bf16x8 ak = *(const bf16x8*)&Ks[cur][(j * 16 + l16) * 64 +
                                                ((ks * 4 + quad) ^ (l16 & 7)) * 8];
                s[j][0] = MFMA16(ak, bq[0][ks], s[j][0]);
                s[j][1] = MFMA16(ak, bq[1][ks], s[j][1]);
            }
        }
        __builtin_amdgcn_s_setprio(0);

        // causal mask: only the last two k-tiles intersect the diagonal band
        if (kb >= 2 * qi) {
#pragma unroll
            for (int qb = 0; qb < 2; ++qb) {
                const int qrow = qi * 128 + wave * 32 + qb * 16 + l16;
#pragma unroll
                for (int j = 0; j < 4; ++j)
#pragma unroll
                    for (int r = 0; r < 4; ++r) {
                        const int key = kb * 64 + j * 16 + quad * 4 + r;
                        if (key > qrow) s[j][qb][r] = -INFINITY;   // exp2 -> 0
                    }
            }
        }

        // p = exp2(s), accumulate l, pack to Ps[q_local][k]
#pragma unroll
        for (int qb = 0; qb < 2; ++qb) {
#pragma unroll
            for (int j = 0; j < 4; ++j) {
                const float p0 = __builtin_amdgcn_exp2f(s[j][qb][0]);
                const float p1 = __builtin_amdgcn_exp2f(s[j][qb][1]);
                const float p2 = __builtin_amdgcn_exp2f(s[j][qb][2]);
                const float p3 = __builtin_amdgcn_exp2f(s[j][qb][3]);
                lp[qb] += (p0 + p1) + (p2 + p3);
                uint2 pw; pw.x = pkbf(p0, p1); pw.y = pkbf(p2, p3);
                *(uint2*)&Ps[(wave * 32 + qb * 16 + l16) * 72 + j * 16 + quad * 4] = pw;
            }
        }

        // O^T += V^T·P^T : every av fragment feeds BOTH q-column blocks.
        // Ps rows are wave-private: same-wave DS order suffices.
        __builtin_amdgcn_s_setprio(1);
#pragma unroll
        for (int ks = 0; ks < 2; ++ks) {
            bf16x8 bp0 = *(const bf16x8*)&Ps[(wave * 32 + l16) * 72 + ks * 32 + quad * 8];
            bf16x8 bp1 = *(const bf16x8*)&Ps[(wave * 32 + 16 + l16) * 72 + ks * 32 + quad * 8];
#pragma unroll
            for (int j = 0; j < 4; ++j) {
                bf16x8 av = *(const bf16x8*)&Vts[cur][(j * 16 + l16) * 64 +
                                                ((ks * 4 + quad) ^ (l16 & 7)) * 8];
                o_acc[j][0] = MFMA16(av, bp0, o_acc[j][0]);
                o_acc[j][1] = MFMA16(av, bp1, o_acc[j][1]);
            }
        }
        __builtin_amdgcn_s_setprio(0);
    }

    // epilogue: per q-column block reduce l, normalize, store
#pragma unroll
    for (int qb = 0; qb < 2; ++qb) {
        float l = lp[qb];
        l += __shfl_xor(l, 16);
        l += __shfl_xor(l, 32);
        const float inv = 1.0f / l;
        const int qrow = qi * 128 + wave * 32 + qb * 16 + l16;
#pragma unroll
        for (int j = 0; j < 4; ++j) {
            uint2 o4;
            o4.x = pkbf(o_acc[j][qb][0] * inv, o_acc[j][qb][1] * inv);
            o4.y = pkbf(o_acc[j][qb][2] * inv, o_acc[j][qb][3] * inv);
            *(uint2*)&O[((size_t)(b * SS + qrow)) * EE + h * DD + j * 16 + quad * 4] = o4;
        }
    }
}

extern "C" void kernel_launch(void* const* d_in, const int* in_sizes, int n_in,
                              void* d_out, int out_size, void* d_ws, size_t ws_size,
                              hipStream_t stream) {
    const float* x      = (const float*)d_in[0];  // [B,S,E] fp32
    const float* W_attn = (const float*)d_in[1];  // [3E,E] fp32
    const float* b_attn = (const float*)d_in[2];  // [3E] fp32
    const float* W_proj = (const float*)d_in[3];  // [E,E] fp32
    const float* b_proj = (const float*)d_in[4];  // [E] fp32
    float* out = (float*)d_out;                   // fp32 [B,S,E]

    // ws layout (u16 elems): xb 4.19M | wab 3.15M | wpb 1.05M | q 4.19M | k 4.19M | vt 4.19M
    u16* xb  = (u16*)d_ws;
    u16* wab = xb + (size_t)4096 * 1024;
    u16* wpb = wab + (size_t)3072 * 1024;
    u16* qw  = wpb + (size_t)1024 * 1024;
    u16* kw  = qw + (size_t)BB * HH * SS * DD;
    u16* vtw = kw + (size_t)BB * HH * SS * DD;
    u16* ow  = xb;                                 // xb dead after gemm_qkv

    convert_all<<<8192, 256, 0, stream>>>(x, W_attn, W_proj, xb);
    gemm_qkv<<<dim3(24, 32), 512, 0, stream>>>(xb, wab, b_attn, qw, kw, vtw);
    attn<<<dim3(32, 16), 256, 0, stream>>>(qw, kw, vtw, ow);
    gemm_proj<<<dim3(64, 8), 512, 0, stream>>>(ow, wpb, b_proj, out);
}

// Round 9
// 171.048 us; speedup vs baseline: 1.0700x; 1.0700x over previous
//
#include <hip/hip_runtime.h>
#include <hip/hip_bf16.h>

typedef unsigned short u16;
typedef unsigned int u32;
typedef float f32x4 __attribute__((ext_vector_type(4)));
typedef short bf16x8 __attribute__((ext_vector_type(8)));

// ---- constants (B=2, S=2048, E=1024, H=16, D=64) ----
#define BB 2
#define SS 2048
#define EE 1024
#define HH 16
#define DD 64
// q pre-scale: 1/sqrt(D) * log2(e) — scores land directly in exp2 domain.
#define QSCALE 0.18033688011f

__device__ __forceinline__ u16 f2bf(float f) {
    union { u32 i; float f; } x; x.f = f;
    return (u16)((x.i + 0x7FFFu + ((x.i >> 16) & 1u)) >> 16);
}
__device__ __forceinline__ u32 pkbf(float a, float b) {
    __hip_bfloat162 h = __float22bfloat162_rn(make_float2(a, b));
    union { __hip_bfloat162 h; u32 u; } c; c.h = h; return c.u;
}

#define MFMA16(a, b, c) __builtin_amdgcn_mfma_f32_16x16x32_bf16((a), (b), (c), 0, 0, 0)

// async global->LDS DMA, 16B per lane; LDS dest = wave-uniform base + lane*16
__device__ __forceinline__ void gld16(const u16* g, u16* l) {
    __builtin_amdgcn_global_load_lds(
        (const __attribute__((address_space(1))) void*)g,
        (__attribute__((address_space(3))) void*)l,
        16, 0, 0);
}

// ============================================================
// fused fp32 -> bf16 convert of x | W_attn | W_proj into contiguous ws
// ============================================================
__global__ __launch_bounds__(256) void convert_all(
    const float* __restrict__ x, const float* __restrict__ wa,
    const float* __restrict__ wp, u16* __restrict__ dst)
{
    const size_t n0 = (size_t)4096 * 1024;
    const size_t n1 = n0 + (size_t)3072 * 1024;
    size_t i = ((size_t)blockIdx.x * 256 + threadIdx.x) * 4;
    const float* s;
    size_t off;
    if (i < n0)      { s = x;  off = 0;  }
    else if (i < n1) { s = wa; off = n0; }
    else             { s = wp; off = n1; }
    float4 v = *(const float4*)(s + (i - off));
    uint2 o;
    o.x = pkbf(v.x, v.y);
    o.y = pkbf(v.z, v.w);
    *(uint2*)(dst + i) = o;
}

// ============================================================
// GEMM1 v5: qkv = x*W_attn^T + b_attn — 8-wave 128x128 tile.
// TAIL FIX: single-buffered staging (32 KB LDS, R3 structure — dbuf
// was proven neutral at 2/CU in R4) + __launch_bounds__(512, 6):
// 6 waves/SIMD = 24 waves/CU = THREE 8-wave blocks resident.
// 768 blocks = 3 x 256 -> zero dispatch tail (v4's 64 KB dbuf gave
// 2/CU -> 768 = 512 + 256: a half-empty tail round, ~20% wasted).
// 3 co-resident blocks overlap each other's DMA drains (v8 lesson).
// VGPR budget 85 @ 6 waves/SIMD; kernel needs ~71 (32 acc + 24 frag).
// grid (24, 32): XCD = x%8 — W n-slices L2-resident (good orientation).
// ============================================================
__global__ __launch_bounds__(512, 6) void gemm_qkv(
    const u16* __restrict__ A, const u16* __restrict__ B, const float* __restrict__ bias,
    u16* __restrict__ Qo, u16* __restrict__ Ko, u16* __restrict__ Vto)
{
    __shared__ __align__(16) u16 SMEM[16384];      // As[128*64] | Bs[128*64]; T aliases
    u16* As = SMEM;
    u16* Bs = SMEM + 8192;
    const int n0 = blockIdx.x * 128, m0 = blockIdx.y * 128;
    const int tid = threadIdx.x;
    const int wave = tid >> 6, lane = tid & 63;
    const int l16 = lane & 15, quad = lane >> 4;
    const int wm = wave >> 2, wn = wave & 3;       // 2x4 wave grid
    const int ldr = lane >> 3;
    const int csw = ((lane & 7) ^ ldr) * 8;        // swizzled k-chunk (elems)

    f32x4 acc[4][2];
#pragma unroll
    for (int i = 0; i < 4; ++i)
#pragma unroll
        for (int j = 0; j < 2; ++j) acc[i][j] = f32x4{0.f, 0.f, 0.f, 0.f};

    const int aorb = wave >> 2;                    // 0: stage A, 1: stage B
    u16* stgbuf = aorb ? Bs : As;
    const u16* stgsrc = aorb ? B : A;
    const int stgbase = aorb ? n0 : m0;

    for (int k0 = 0; k0 < 1024; k0 += 64) {
        __syncthreads();
#pragma unroll
        for (int t = 0; t < 4; ++t) {
            const int c = (wave & 3) * 4 + t;      // 0..15
            const int row = c * 8 + ldr;
            gld16(stgsrc + (size_t)(stgbase + row) * 1024 + k0 + csw,
                  &stgbuf[c * 512 + lane * 8]);
        }
        __syncthreads();
#pragma unroll
        for (int ks = 0; ks < 2; ++ks) {
            bf16x8 af[4], bf[2];
#pragma unroll
            for (int i = 0; i < 4; ++i)
                af[i] = *(const bf16x8*)&As[(wm * 64 + i * 16 + l16) * 64 +
                                            ((ks * 4 + quad) ^ (l16 & 7)) * 8];
#pragma unroll
            for (int j = 0; j < 2; ++j)
                bf[j] = *(const bf16x8*)&Bs[(wn * 32 + j * 16 + l16) * 64 +
                                            ((ks * 4 + quad) ^ (l16 & 7)) * 8];
#pragma unroll
            for (int i = 0; i < 4; ++i)
#pragma unroll
                for (int j = 0; j < 2; ++j)
                    acc[i][j] = MFMA16(af[i], bf[j], acc[i][j]);
        }
    }

    const int part = blockIdx.x >> 3;              // 0=q,1=k,2=v
    const int hbase = (blockIdx.x & 7) << 1;
    if (part != 2) {
        const int h = hbase + (wn >> 1);           // uniform per wave
#pragma unroll
        for (int j = 0; j < 2; ++j) {
            const int f = n0 + wn * 32 + j * 16 + l16;
            const int d = f & 63;
            const float bj = bias[f];
#pragma unroll
            for (int i = 0; i < 4; ++i) {
#pragma unroll
                for (int r = 0; r < 4; ++r) {
                    const int m = m0 + wm * 64 + i * 16 + quad * 4 + r;
                    const int b = m >> 11, s = m & 2047;
                    const float val = acc[i][j][r] + bj;
                    if (part == 0)
                        Qo[(((size_t)(b * HH + h)) * SS + s) * DD + d] = f2bf(val * QSCALE);
                    else
                        Ko[(((size_t)(b * HH + h)) * SS + s) * DD + d] = f2bf(val);
                }
            }
        }
    } else {
        // V: transpose C-tile (128 m x 128 f) through T (aliases SMEM),
        // two m-half passes, coalesced 8B stores to [B,H,D,S].
        u16* T = SMEM;                             // 128 x 72 = 18432 B
#pragma unroll
        for (int wmr = 0; wmr < 2; ++wmr) {
            __syncthreads();
            if (wm == wmr) {
#pragma unroll
                for (int j = 0; j < 2; ++j) {
                    const float bj = bias[n0 + wn * 32 + j * 16 + l16];
#pragma unroll
                    for (int i = 0; i < 4; ++i) {
                        uint2 pw;
                        pw.x = pkbf(acc[i][j][0] + bj, acc[i][j][1] + bj);
                        pw.y = pkbf(acc[i][j][2] + bj, acc[i][j][3] + bj);
                        *(uint2*)&T[(wn * 32 + j * 16 + l16) * 72 + i * 16 + quad * 4] = pw;
                    }
                }
            }
            __syncthreads();
            const int frow = tid >> 2;             // 0..127 (f_local)
            const int qtr = tid & 3;
            const int h = hbase + (frow >> 6);
            const int d = frow & 63;
            const int mg = m0 + wmr * 64;
            const int b = mg >> 11, sbase = mg & 2047;
            u16* dstrow = Vto + (((size_t)(b * HH + h)) * DD + d) * SS + sbase;
#pragma unroll
            for (int l = 0; l < 4; ++l) {
                const int mo = qtr * 16 + l * 4;
                *(uint2*)(dstrow + mo) = *(const uint2*)&T[frow * 72 + mo];
            }
        }
    }
}

// ============================================================
// GEMM2 v5: out = o*W_proj^T + b_proj (fp32) — 64x128 tile, 8 waves,
// double-buffered staging, grid (64, 8) (XCD = m%8: A-rows L2-local,
// W_proj 2.1 MB L2-resident — R6 win, kept). 512 blocks = 2/CU exact.
// ============================================================
__global__ __launch_bounds__(512, 4) void gemm_proj(
    const u16* __restrict__ A, const u16* __restrict__ B, const float* __restrict__ bias,
    float* __restrict__ out)
{
    __shared__ __align__(16) u16 SMEM[2][12288];   // [buf]{As[64*64] | Bs[128*64]}
    const int n0 = blockIdx.y * 128, m0 = blockIdx.x * 64;
    const int tid = threadIdx.x;
    const int wave = tid >> 6, lane = tid & 63;
    const int l16 = lane & 15, quad = lane >> 4;
    const int wm = wave >> 2, wn = wave & 3;       // 2x4 wave grid
    const int ldr = lane >> 3;
    const int csw = ((lane & 7) ^ ldr) * 8;

    f32x4 acc[2][2];
#pragma unroll
    for (int i = 0; i < 2; ++i)
#pragma unroll
        for (int j = 0; j < 2; ++j) acc[i][j] = f32x4{0.f, 0.f, 0.f, 0.f};

    auto stage = [&](int k0, int buf) {
#pragma unroll
        for (int t = 0; t < 3; ++t) {
            const int c = wave * 3 + t;            // 0..23: A chunks 0-7, B 8-23
            if (c < 8) {
                const int row = c * 8 + ldr;
                gld16(A + (size_t)(m0 + row) * 1024 + k0 + csw,
                      &SMEM[buf][c * 512 + lane * 8]);
            } else {
                const int c2 = c - 8;
                const int row = c2 * 8 + ldr;
                gld16(B + (size_t)(n0 + row) * 1024 + k0 + csw,
                      &SMEM[buf][4096 + c2 * 512 + lane * 8]);
            }
        }
    };

    stage(0, 0);                                   // prologue
    for (int k0 = 0; k0 < 1024; k0 += 64) {
        const int cur = (k0 >> 6) & 1;
        __syncthreads();
        if (k0 + 64 < 1024) stage(k0 + 64, cur ^ 1);
        const u16* As = SMEM[cur];
        const u16* Bs = SMEM[cur] + 4096;
#pragma unroll
        for (int ks = 0; ks < 2; ++ks) {
            bf16x8 af[2], bf[2];
#pragma unroll
            for (int i = 0; i < 2; ++i)
                af[i] = *(const bf16x8*)&As[(wm * 32 + i * 16 + l16) * 64 +
                                            ((ks * 4 + quad) ^ (l16 & 7)) * 8];
#pragma unroll
            for (int j = 0; j < 2; ++j)
                bf[j] = *(const bf16x8*)&Bs[(wn * 32 + j * 16 + l16) * 64 +
                                            ((ks * 4 + quad) ^ (l16 & 7)) * 8];
#pragma unroll
            for (int i = 0; i < 2; ++i)
#pragma unroll
                for (int j = 0; j < 2; ++j)
                    acc[i][j] = MFMA16(af[i], bf[j], acc[i][j]);
        }
    }
#pragma unroll
    for (int j = 0; j < 2; ++j) {
        const int f = n0 + wn * 32 + j * 16 + l16;
        const float bj = bias[f];
#pragma unroll
        for (int i = 0; i < 2; ++i) {
#pragma unroll
            for (int r = 0; r < 4; ++r) {
                const int m = m0 + wm * 32 + i * 16 + quad * 4 + r;
                out[(size_t)m * EE + f] = acc[i][j][r] + bj;
            }
        }
    }
}

// ============================================================
// MFMA flash attention v8 (REVERT of v10): best-measured attn (~38 µs).
// Constraint set mapped over R5-R7: need >=2 blocks/CU (v9: 1/CU ->
// exposed drains, +11 µs) AND equal per-block work (v10: unpaired
// triangular -> max-CU 48 vs 20 phase-units, +9 µs) AND K/V fragment
// reuse — with 256-thr blocks all three can't hold; v8 is the local opt.
// v8: 512 blocks x 256 thr (2/CU), dbuf K/V pairs, two k-tiles per
// barrier, pair-balanced q-tiles (33 phases/block), setprio.
// grid (32,16): x = bh -> XCD = bh % 8 (L2 locality, round 2 win).
// ============================================================
__global__ __launch_bounds__(256, 2) void attn(
    const u16* __restrict__ Q, const u16* __restrict__ K, const u16* __restrict__ VT,
    u16* __restrict__ O)
{
    const int p = blockIdx.y;              // 0..15  (pair index)
    const int bh = blockIdx.x;             // 0..31  -> XCD = bh % 8
    const int tid = threadIdx.x;
    const int wave = tid >> 6, lane = tid & 63;
    const int l16 = lane & 15, quad = lane >> 4;
    const int ldr = lane >> 3;
    const int csw = ((lane & 7) ^ ldr) * 8;
    __shared__ __align__(16) u16 Ks[2][2][64 * 64];   // [buf][sub]
    __shared__ __align__(16) u16 Vts[2][2][64 * 64];
    __shared__ __align__(16) u16 Ps[64 * 72];

    const u16* qptr = Q + (size_t)bh * SS * DD;
    const u16* kptr = K + (size_t)bh * SS * DD;
    const u16* vtptr = VT + (size_t)bh * DD * SS;
    const int b = bh >> 4, h = bh & 15;

    // stage k-tile `t` (and matching V^T columns) into [buf][sub]
    auto stage = [&](int t, int buf, int sub) {
#pragma unroll
        for (int c = 0; c < 2; ++c) {
            const int a0 = wave * 2 + c;
            const int row = a0 * 8 + ldr;
            gld16(kptr + (size_t)(t * 64 + row) * DD + csw,
                  &Ks[buf][sub][a0 * 512 + lane * 8]);
            gld16(vtptr + (size_t)row * SS + t * 64 + csw,
                  &Vts[buf][sub][a0 * 512 + lane * 8]);
        }
    };

    for (int half = 0; half < 2; ++half) {
        const int qb = half ? p : 31 - p;          // long tile first
        const int qrow = qb * 64 + wave * 16 + l16;   // this lane's query
        bf16x8 bq[2];
#pragma unroll
        for (int ks = 0; ks < 2; ++ks)
            bq[ks] = *(const bf16x8*)(qptr + (size_t)qrow * DD + ks * 32 + quad * 8);

        float lp = 0.f;                    // per-lane partial l
        f32x4 o_acc[4];
#pragma unroll
        for (int j = 0; j < 4; ++j) o_acc[j] = f32x4{0.f, 0.f, 0.f, 0.f};

        // per-subtile compute: QK^T -> masked exp2 -> P -> O += V^T P^T
        auto tile_compute = [&](const u16* Kb, const u16* Vb, int t) {
            f32x4 s[4];
#pragma unroll
            for (int j = 0; j < 4; ++j) s[j] = f32x4{0.f, 0.f, 0.f, 0.f};
            __builtin_amdgcn_s_setprio(1);
#pragma unroll
            for (int ks = 0; ks < 2; ++ks) {
#pragma unroll
                for (int j = 0; j < 4; ++j) {
                    bf16x8 ak = *(const bf16x8*)&Kb[(j * 16 + l16) * 64 +
                                                    ((ks * 4 + quad) ^ (l16 & 7)) * 8];
                    s[j] = MFMA16(ak, bq[ks], s[j]);
                }
            }
            __builtin_amdgcn_s_setprio(0);
            if (t == qb) {                 // mask only on the diagonal tile
#pragma unroll
                for (int j = 0; j < 4; ++j)
#pragma unroll
                    for (int r = 0; r < 4; ++r) {
                        const int key = t * 64 + j * 16 + quad * 4 + r;
                        if (key > qrow) s[j][r] = -INFINITY;   // exp2 -> 0
                    }
            }
#pragma unroll
            for (int j = 0; j < 4; ++j) {
                const float p0 = __builtin_amdgcn_exp2f(s[j][0]);
                const float p1 = __builtin_amdgcn_exp2f(s[j][1]);
                const float p2 = __builtin_amdgcn_exp2f(s[j][2]);
                const float p3 = __builtin_amdgcn_exp2f(s[j][3]);
                lp += (p0 + p1) + (p2 + p3);
                uint2 pw; pw.x = pkbf(p0, p1); pw.y = pkbf(p2, p3);
                *(uint2*)&Ps[(wave * 16 + l16) * 72 + j * 16 + quad * 4] = pw;
            }
            // O^T += V^T·P^T (Ps wave-private: lgkm ordering suffices)
            __builtin_amdgcn_s_setprio(1);
#pragma unroll
            for (int ks = 0; ks < 2; ++ks) {
                bf16x8 bp = *(const bf16x8*)&Ps[(wave * 16 + l16) * 72 + ks * 32 + quad * 8];
#pragma unroll
                for (int j = 0; j < 4; ++j) {
                    bf16x8 av = *(const bf16x8*)&Vb[(j * 16 + l16) * 64 +
                                                    ((ks * 4 + quad) ^ (l16 & 7)) * 8];
                    o_acc[j] = MFMA16(av, bp, o_acc[j]);
                }
            }
            __builtin_amdgcn_s_setprio(0);
        };

        // protect buf0 from the previous half's in-flight readers
        __syncthreads();
        // prologue: stage tile pair {0, min(1,qb)} into buf 0
        stage(0, 0, 0);
        stage(qb < 1 ? qb : 1, 0, 1);

        for (int kb = 0; kb <= qb; kb += 2) {
            const int cur = (kb >> 1) & 1;
            // vmcnt(0)+barrier (compiler-emitted): buf[cur] pair ready,
            // buf[cur^1] has no readers left.
            __syncthreads();
            if (kb + 2 <= qb) {            // prefetch next pair into buf^1
                stage(kb + 2, cur ^ 1, 0);
                const int t3 = kb + 3 > qb ? qb : kb + 3;   // clamp (no OOB)
                stage(t3, cur ^ 1, 1);
            }
            tile_compute(Ks[cur][0], Vts[cur][0], kb);
            if (kb + 1 <= qb)
                tile_compute(Ks[cur][1], Vts[cur][1], kb + 1);
        }

        // epilogue: quad-reduce l once, normalize, store (lane owns query qrow)
        float l = lp;
        l += __shfl_xor(l, 16);
        l += __shfl_xor(l, 32);
        const float inv = 1.0f / l;
#pragma unroll
        for (int j = 0; j < 4; ++j) {
            uint2 o4;
            o4.x = pkbf(o_acc[j][0] * inv, o_acc[j][1] * inv);
            o4.y = pkbf(o_acc[j][2] * inv, o_acc[j][3] * inv);
            *(uint2*)&O[((size_t)(b * SS + qrow)) * EE + h * DD + j * 16 + quad * 4] = o4;
        }
    }
}

extern "C" void kernel_launch(void* const* d_in, const int* in_sizes, int n_in,
                              void* d_out, int out_size, void* d_ws, size_t ws_size,
                              hipStream_t stream) {
    const float* x      = (const float*)d_in[0];  // [B,S,E] fp32
    const float* W_attn = (const float*)d_in[1];  // [3E,E] fp32
    const float* b_attn = (const float*)d_in[2];  // [3E] fp32
    const float* W_proj = (const float*)d_in[3];  // [E,E] fp32
    const float* b_proj = (const float*)d_in[4];  // [E] fp32
    float* out = (float*)d_out;                   // fp32 [B,S,E]

    // ws layout (u16 elems): xb 4.19M | wab 3.15M | wpb 1.05M | q 4.19M | k 4.19M | vt 4.19M
    u16* xb  = (u16*)d_ws;
    u16* wab = xb + (size_t)4096 * 1024;
    u16* wpb = wab + (size_t)3072 * 1024;
    u16* qw  = wpb + (size_t)1024 * 1024;
    u16* kw  = qw + (size_t)BB * HH * SS * DD;
    u16* vtw = kw + (size_t)BB * HH * SS * DD;
    u16* ow  = xb;                                 // xb dead after gemm_qkv

    convert_all<<<8192, 256, 0, stream>>>(x, W_attn, W_proj, xb);
    gemm_qkv<<<dim3(24, 32), 512, 0, stream>>>(xb, wab, b_attn, qw, kw, vtw);
    attn<<<dim3(32, 16), 256, 0, stream>>>(qw, kw, vtw, ow);
    gemm_proj<<<dim3(64, 8), 512, 0, stream>>>(ow, wpb, b_proj, out);
}